// Round 13
// baseline (320.252 us; speedup 1.0000x reference)
//
#include <hip/hip_runtime.h>
#include <cfloat>

#define NBATCH 8
#define NPTS   4096
#define KNN    16
#define CAP    24   // pass-2 collection capacity per point per half
#define JH     2048 // candidates per half

typedef unsigned short u16;
typedef unsigned int   u32;
typedef __attribute__((ext_vector_type(8))) short short8;
typedef __attribute__((ext_vector_type(4))) float f32x4;

__device__ __forceinline__ float relu_f(float x) { return x > 0.f ? x : 0.f; }

// round-to-nearest-even bf16 split: x = hi + lo, packed hi<<16|lo
__device__ __forceinline__ u32 bf16_split_pack(float v)
{
    unsigned u = __float_as_uint(v);
    unsigned hb = (u + 0x7FFFu + ((u >> 16) & 1u)) >> 16;
    float hf = __uint_as_float(hb << 16);
    float l = v - hf;                      // exact
    unsigned ul = __float_as_uint(l);
    unsigned lb = (ul + 0x7FFFu + ((ul >> 16) & 1u)) >> 16;
    return (hb << 16) | (lb & 0xFFFFu);
}

// 8 packed u32 -> short8 of hi bf16 + short8 of lo bf16 (v_perm_b32)
__device__ __forceinline__ void unpack8(uint4 a, uint4 b, short8& h, short8& l)
{
    union { unsigned u[4]; short8 s; } H, L;
    H.u[0] = __builtin_amdgcn_perm(a.y, a.x, 0x07060302);
    H.u[1] = __builtin_amdgcn_perm(a.w, a.z, 0x07060302);
    H.u[2] = __builtin_amdgcn_perm(b.y, b.x, 0x07060302);
    H.u[3] = __builtin_amdgcn_perm(b.w, b.z, 0x07060302);
    L.u[0] = __builtin_amdgcn_perm(a.y, a.x, 0x05040100);
    L.u[1] = __builtin_amdgcn_perm(a.w, a.z, 0x05040100);
    L.u[2] = __builtin_amdgcn_perm(b.y, b.x, 0x05040100);
    L.u[3] = __builtin_amdgcn_perm(b.w, b.z, 0x05040100);
    h = H.s; l = L.s;
}

// ---------------------------------------------------------------------------
// K0: pts4[b][j] = (x, y, z, xx) — candidate table for scalar-broadcast knn.
// xx uses the exact same FP ops as all prior rounds.
// ---------------------------------------------------------------------------
__global__ __launch_bounds__(256)
void pts4_kernel(const float* __restrict__ pts, float4* __restrict__ pts4)
{
    int t = blockIdx.x * 256 + threadIdx.x;   // 0..32767
    int b = t >> 12, j = t & 4095;
    const float* pb = pts + (size_t)b * 3 * NPTS;
    float x = pb[j], y = pb[NPTS + j], z = pb[2 * NPTS + j];
    float xx = __fadd_rn(__fadd_rn(__fmul_rn(x, x), __fmul_rn(y, y)),
                         __fmul_rn(z, z));
    pts4[t] = make_float4(x, y, z, xx);
}

// ---------------------------------------------------------------------------
// K1a: KNN half-range pass, wave = 64 POINTS x serial candidates.
// grid (64 ptgroups, 2 halves, 8 batch), block 256 = 4 waves; wave w covers
// candidates [half*2048 + w*512, +512) — candidate address is WAVE-UNIFORM
// (one 16B broadcast request/step, no ds_read in the hot loop; the R9-R12
// structure was LDS-issue-bound at ~12cyc/candidate).
// Pass1: branchless top-8 values/wave-segment (8 med3 + fmax + 4 dist VALU).
// thr = 16th of the 4x8 union (subset stat <= per-half t*: safe).
// Pass2: threshold rescan, LDS-atomic collect; CAP overflow -> exact serial
// scan of the half. Output per-half top-16 (pd,idx) by (pd desc, idx asc).
// ---------------------------------------------------------------------------
__global__ __launch_bounds__(256)
void knn_half_kernel(const float4* __restrict__ pts4,
                     float* __restrict__ ppd, int* __restrict__ pix)
{
    __shared__ float kl[64 * 32];     // [pt][wave*8+s]   8KB
    __shared__ float thr[64];
    __shared__ int   cnt[64];
    __shared__ float pv[64 * CAP];    // 6KB
    __shared__ int   pi[64 * CAP];    // 6KB

    const int b = blockIdx.z, half = blockIdx.y, tid = threadIdx.x;
    const int l = tid & 63;
    const int w = __builtin_amdgcn_readfirstlane(tid >> 6);   // wave id (SGPR)
    const int n = blockIdx.x * 64 + l;
    const float4* pb4 = pts4 + (size_t)b * NPTS;
    const float4 sp = pb4[n];
    const int j0 = half * JH + w * 512;

    float k8[8];
#pragma unroll
    for (int s = 0; s < 8; ++s) k8[s] = -FLT_MAX;

    // ---- PASS 1: 512 candidates, uniform-address loads ----
#pragma unroll 4
    for (int j = 0; j < 512; ++j) {
        float4 c = pb4[j0 + j];
        float dt = __fmaf_rn(sp.x, c.x, __fmaf_rn(sp.y, c.y, __fmul_rn(sp.z, c.z)));
        float pd = __fmaf_rn(2.f, dt, -c.w);
        float old0 = k8[0];
#pragma unroll
        for (int s = 7; s >= 1; --s)
            k8[s] = __builtin_amdgcn_fmed3f(k8[s - 1], k8[s], pd);
        k8[0] = fmaxf(old0, pd);
    }
#pragma unroll
    for (int s = 0; s < 8; ++s) kl[l * 32 + w * 8 + s] = k8[s];
    __syncthreads();

    if (tid < 64) {   // 4-way merge of sorted-desc 8-lists; thr = 16th pick
        const float* L = kl + tid * 32;
        int p0 = 0, p1 = 0, p2 = 0, p3 = 0;
        float tv = 0.f;
        for (int o = 0; o < 16; ++o) {
            float v0 = (p0 < 8) ? L[p0]      : -FLT_MAX;
            float v1 = (p1 < 8) ? L[8 + p1]  : -FLT_MAX;
            float v2 = (p2 < 8) ? L[16 + p2] : -FLT_MAX;
            float v3 = (p3 < 8) ? L[24 + p3] : -FLT_MAX;
            float m = fmaxf(fmaxf(v0, v1), fmaxf(v2, v3));
            tv = m;
            if      (v0 == m) ++p0;
            else if (v1 == m) ++p1;
            else if (v2 == m) ++p2;
            else              ++p3;
        }
        thr[tid] = tv;
        cnt[tid] = 0;
    }
    __syncthreads();
    const float myThr = thr[l];

    // ---- PASS 2: rescan with threshold (identical FP ops) ----
    for (int j = 0; j < 512; ++j) {
        float4 c = pb4[j0 + j];
        float dt = __fmaf_rn(sp.x, c.x, __fmaf_rn(sp.y, c.y, __fmul_rn(sp.z, c.z)));
        float pd = __fmaf_rn(2.f, dt, -c.w);
        if (pd >= myThr) {
            int pos = atomicAdd(&cnt[l], 1);
            if (pos < CAP) { pv[l * CAP + pos] = pd; pi[l * CAP + pos] = j0 + j; }
        }
    }
    __syncthreads();

    if (tid < 64) {
        const int np = blockIdx.x * 64 + tid;
        float* od = ppd + (((size_t)b * 2 + half) * NPTS + np) * KNN;
        int*   oi = pix + (((size_t)b * 2 + half) * NPTS + np) * KNN;
        int c = cnt[tid];
        if (c <= CAP) {
            // exact top-16 selection by (pd desc, idx asc) — collection order
            // across waves is nondeterministic but the total order makes the
            // output deterministic.
            float* v  = pv + tid * CAP;
            int*   ix = pi + tid * CAP;
            for (int o = 0; o < 16; ++o) {
                int best = o;
                for (int q = o + 1; q < c; ++q) {
                    float vq = v[q], vb = v[best];
                    if (vq > vb || (vq == vb && ix[q] < ix[best])) best = q;
                }
                float tv = v[o]; v[o] = v[best]; v[best] = tv;
                int   ti = ix[o]; ix[o] = ix[best]; ix[best] = ti;
                od[o] = v[o]; oi[o] = ix[o];
            }
        } else {
            // rare overflow: exact serial scan of this half
            float4 q4 = pb4[np];
            float v16[16]; int i16[16];
#pragma unroll
            for (int s = 0; s < 16; ++s) { v16[s] = -FLT_MAX; i16[s] = 0; }
            for (int j = half * JH; j < half * JH + JH; ++j) {
                float4 c = pb4[j];
                float dt = __fmaf_rn(q4.x, c.x, __fmaf_rn(q4.y, c.y,
                                     __fmul_rn(q4.z, c.z)));
                float pd = __fmaf_rn(2.f, dt, -c.w);
                if (pd > v16[15]) {
                    int s = 15;
                    while (s > 0 && pd > v16[s - 1]) {
                        v16[s] = v16[s - 1]; i16[s] = i16[s - 1]; --s;
                    }
                    v16[s] = pd; i16[s] = j;
                }
            }
            for (int o = 0; o < 16; ++o) { od[o] = v16[o]; oi[o] = i16[o]; }
        }
    }
}

// ---------------------------------------------------------------------------
// K1b: merge the two per-half top-16 lists -> final idx. Halves have disjoint
// idx ranges (h0 < 2048 <= h1) so tie -> takeA gives lower idx = lax.top_k.
// ---------------------------------------------------------------------------
__global__ __launch_bounds__(256)
void knn_merge_kernel(const float* __restrict__ ppd, const int* __restrict__ pix,
                      int* __restrict__ idxout)
{
    int t = blockIdx.x * 256 + threadIdx.x;   // 0..32767
    int b = t >> 12, n = t & 4095;
    const float* A  = ppd + (((size_t)b * 2 + 0) * NPTS + n) * KNN;
    const int*   Ai = pix + (((size_t)b * 2 + 0) * NPTS + n) * KNN;
    const float* B  = ppd + (((size_t)b * 2 + 1) * NPTS + n) * KNN;
    const int*   Bi = pix + (((size_t)b * 2 + 1) * NPTS + n) * KNN;
    int* out = idxout + ((size_t)b * NPTS + n) * KNN;
    int ia = 0, ib = 0;
#pragma unroll
    for (int o = 0; o < 16; ++o) {
        float va = A[ia], vb = B[ib];
        bool takeA = (va > vb) || (va == vb && Ai[ia] < Bi[ib]);
        out[o] = takeA ? Ai[ia] : Bi[ib];
        ia += takeA; ib += !takeA;
    }
}

// ---------------------------------------------------------------------------
// K2: local_cov + mlp1 (12->64->64->64), weights in LDS, 4x4 tiles. (unchanged)
// ---------------------------------------------------------------------------
__global__ __launch_bounds__(256)
void cov_mlp1_kernel(const float* __restrict__ pts, const int* __restrict__ idx,
                     const float* __restrict__ w1, const float* __restrict__ b1,
                     const float* __restrict__ w2, const float* __restrict__ b2,
                     const float* __restrict__ w3, const float* __restrict__ b3,
                     float* __restrict__ h3out)
{
    __shared__ __align__(16) float cov[64 * 16];
    __shared__ __align__(16) float w1s[64 * 16];
    __shared__ __align__(16) float w2s[64 * 68];
    __shared__ __align__(16) float w3s[64 * 68];
    __shared__ __align__(16) float hA[64 * 68];
    __shared__ __align__(16) float hB[64 * 68];

    const int b = blockIdx.y, tid = threadIdx.x;
    const int n0 = blockIdx.x * 64;
    const int pq = tid >> 4, cq = tid & 15;

    for (int i = tid; i < 64 * 4; i += 256) {
        int p = i >> 2, k4 = i & 3;
        float4 v = make_float4(0.f, 0.f, 0.f, 0.f);
        if (k4 < 3) v = *(const float4*)(w1 + p * 12 + k4 * 4);
        ((float4*)(w1s + p * 16))[k4] = v;
    }
    for (int i = tid; i < 64 * 16; i += 256) {
        int p = i >> 4, k4 = i & 15;
        ((float4*)(w2s + p * 68))[k4] = ((const float4*)(w2 + p * 64))[k4];
        ((float4*)(w3s + p * 68))[k4] = ((const float4*)(w3 + p * 64))[k4];
    }
    if (tid < 64) {
        const int n = n0 + tid;
        const int* ip = idx + ((size_t)b * NPTS + n) * KNN;
        int j0 = ip[0], j1 = ip[1];
        const float* pb = pts + (size_t)b * 3 * NPTS;
        float px = pb[n],  py = pb[NPTS + n],  pz = pb[2 * NPTS + n];
        float ax = pb[j0], ay = pb[NPTS + j0], az = pb[2 * NPTS + j0];
        float bx = pb[j1], by = pb[NPTS + j1], bz = pb[2 * NPTS + j1];
        float* cv = cov + tid * 16;
        cv[0] = px; cv[1] = py; cv[2] = pz;
        cv[3] = ax * bx; cv[4]  = ax * by; cv[5]  = ax * bz;
        cv[6] = ay * bx; cv[7]  = ay * by; cv[8]  = ay * bz;
        cv[9] = az * bx; cv[10] = az * by; cv[11] = az * bz;
        cv[12] = 0.f; cv[13] = 0.f; cv[14] = 0.f; cv[15] = 0.f;
    }
    __syncthreads();

    {   // layer1: 12(16)->64
        float acc[4][4];
#pragma unroll
        for (int i = 0; i < 4; ++i)
#pragma unroll
            for (int j = 0; j < 4; ++j) acc[i][j] = 0.f;
        const float4* X4 = (const float4*)cov;
        const float4* W4 = (const float4*)w1s;
#pragma unroll
        for (int k4 = 0; k4 < 4; ++k4) {
            float4 xa[4], wb[4];
#pragma unroll
            for (int i = 0; i < 4; ++i) xa[i] = X4[(pq * 4 + i) * 4 + k4];
#pragma unroll
            for (int j = 0; j < 4; ++j) wb[j] = W4[(cq + 16 * j) * 4 + k4];
#pragma unroll
            for (int i = 0; i < 4; ++i)
#pragma unroll
                for (int j = 0; j < 4; ++j)
                    acc[i][j] += xa[i].x * wb[j].x + xa[i].y * wb[j].y
                               + xa[i].z * wb[j].z + xa[i].w * wb[j].w;
        }
#pragma unroll
        for (int j = 0; j < 4; ++j) {
            int c = cq + 16 * j;
            float bias = b1[c];
#pragma unroll
            for (int i = 0; i < 4; ++i)
                hA[(pq * 4 + i) * 68 + c] = relu_f(acc[i][j] + bias);
        }
    }
    __syncthreads();

    {   // layer2: 64->64
        float acc[4][4];
#pragma unroll
        for (int i = 0; i < 4; ++i)
#pragma unroll
            for (int j = 0; j < 4; ++j) acc[i][j] = 0.f;
        const float4* X4 = (const float4*)hA;
        const float4* W4 = (const float4*)w2s;
        for (int k4 = 0; k4 < 16; ++k4) {
            float4 xa[4], wb[4];
#pragma unroll
            for (int i = 0; i < 4; ++i) xa[i] = X4[(pq * 4 + i) * 17 + k4];
#pragma unroll
            for (int j = 0; j < 4; ++j) wb[j] = W4[(cq + 16 * j) * 17 + k4];
#pragma unroll
            for (int i = 0; i < 4; ++i)
#pragma unroll
                for (int j = 0; j < 4; ++j)
                    acc[i][j] += xa[i].x * wb[j].x + xa[i].y * wb[j].y
                               + xa[i].z * wb[j].z + xa[i].w * wb[j].w;
        }
#pragma unroll
        for (int j = 0; j < 4; ++j) {
            int c = cq + 16 * j;
            float bias = b2[c];
#pragma unroll
            for (int i = 0; i < 4; ++i)
                hB[(pq * 4 + i) * 68 + c] = relu_f(acc[i][j] + bias);
        }
    }
    __syncthreads();

    {   // layer3: 64->64 -> global
        float acc[4][4];
#pragma unroll
        for (int i = 0; i < 4; ++i)
#pragma unroll
            for (int j = 0; j < 4; ++j) acc[i][j] = 0.f;
        const float4* X4 = (const float4*)hB;
        const float4* W4 = (const float4*)w3s;
        for (int k4 = 0; k4 < 16; ++k4) {
            float4 xa[4], wb[4];
#pragma unroll
            for (int i = 0; i < 4; ++i) xa[i] = X4[(pq * 4 + i) * 17 + k4];
#pragma unroll
            for (int j = 0; j < 4; ++j) wb[j] = W4[(cq + 16 * j) * 17 + k4];
#pragma unroll
            for (int i = 0; i < 4; ++i)
#pragma unroll
                for (int j = 0; j < 4; ++j)
                    acc[i][j] += xa[i].x * wb[j].x + xa[i].y * wb[j].y
                               + xa[i].z * wb[j].z + xa[i].w * wb[j].w;
        }
#pragma unroll
        for (int j = 0; j < 4; ++j) {
            int c = cq + 16 * j;
            float bias = b3[c];
#pragma unroll
            for (int i = 0; i < 4; ++i)
                h3out[((size_t)b * NPTS + n0 + pq * 4 + i) * 64 + c] =
                    relu_f(acc[i][j] + bias);
        }
    }
}

// ---------------------------------------------------------------------------
// K3: neighbor max-pool (64ch), float4 per thread.
// ---------------------------------------------------------------------------
template <int DV4>
__global__ __launch_bounds__(256)
void maxpool4_kernel(const float4* __restrict__ f, const int* __restrict__ idx,
                     float4* __restrict__ out)
{
    constexpr int SH = (DV4 == 16) ? 4 : 5;
    int t = blockIdx.x * 256 + threadIdx.x;
    int d4 = t & (DV4 - 1);
    int n  = (t >> SH) & (NPTS - 1);
    int b  = t >> (SH + 12);
    const int* ip = idx + ((size_t)b * NPTS + n) * KNN;
    const float4* fb = f + (size_t)b * NPTS * DV4;
    float4 v = make_float4(-FLT_MAX, -FLT_MAX, -FLT_MAX, -FLT_MAX);
#pragma unroll
    for (int k = 0; k < KNN; ++k) {
        float4 c = fb[(size_t)ip[k] * DV4 + d4];
        v.x = fmaxf(v.x, c.x); v.y = fmaxf(v.y, c.y);
        v.z = fmaxf(v.z, c.z); v.w = fmaxf(v.w, c.w);
    }
    out[t] = v;
}

// ---------------------------------------------------------------------------
// K4: t1 = L1(64->64) (no relu); y1 = relu(C1(64->128)) (unchanged)
// ---------------------------------------------------------------------------
__global__ __launch_bounds__(256)
void lin_conv1_kernel(const float* __restrict__ xin,
                      const float* __restrict__ l1w, const float* __restrict__ l1b,
                      const float* __restrict__ c1w, const float* __restrict__ c1b,
                      float* __restrict__ yout)
{
    __shared__ __align__(16) float sx[64 * 68];
    __shared__ __align__(16) float wbuf[64 * 68];
    __shared__ __align__(16) float t1[64 * 68];
    const int b = blockIdx.y, tid = threadIdx.x;
    const int n0 = blockIdx.x * 64;
    const int pq = tid >> 4, cq = tid & 15;

    for (int i = tid; i < 64 * 16; i += 256) {
        int p = i >> 4, k4 = i & 15;
        ((float4*)(sx + p * 68))[k4] =
            ((const float4*)(xin + ((size_t)b * NPTS + n0 + p) * 64))[k4];
        ((float4*)(wbuf + p * 68))[k4] = ((const float4*)(l1w + p * 64))[k4];
    }
    __syncthreads();

    {   // L1: 64->64, no relu, +bias -> t1
        float acc[4][4];
#pragma unroll
        for (int i = 0; i < 4; ++i)
#pragma unroll
            for (int j = 0; j < 4; ++j) acc[i][j] = 0.f;
        const float4* X4 = (const float4*)sx;
        const float4* W4 = (const float4*)wbuf;
        for (int k4 = 0; k4 < 16; ++k4) {
            float4 xa[4], wb[4];
#pragma unroll
            for (int i = 0; i < 4; ++i) xa[i] = X4[(pq * 4 + i) * 17 + k4];
#pragma unroll
            for (int j = 0; j < 4; ++j) wb[j] = W4[(cq + 16 * j) * 17 + k4];
#pragma unroll
            for (int i = 0; i < 4; ++i)
#pragma unroll
                for (int j = 0; j < 4; ++j)
                    acc[i][j] += xa[i].x * wb[j].x + xa[i].y * wb[j].y
                               + xa[i].z * wb[j].z + xa[i].w * wb[j].w;
        }
#pragma unroll
        for (int j = 0; j < 4; ++j) {
            int c = cq + 16 * j;
            float bias = l1b[c];
#pragma unroll
            for (int i = 0; i < 4; ++i)
                t1[(pq * 4 + i) * 68 + c] = acc[i][j] + bias;
        }
    }

    for (int g = 0; g < 2; ++g) {
        __syncthreads();
        for (int i = tid; i < 64 * 16; i += 256) {
            int p = i >> 4, k4 = i & 15;
            ((float4*)(wbuf + p * 68))[k4] =
                ((const float4*)(c1w + (size_t)(g * 64 + p) * 64))[k4];
        }
        __syncthreads();
        float acc[4][4];
#pragma unroll
        for (int i = 0; i < 4; ++i)
#pragma unroll
            for (int j = 0; j < 4; ++j) acc[i][j] = 0.f;
        const float4* X4 = (const float4*)t1;
        const float4* W4 = (const float4*)wbuf;
        for (int k4 = 0; k4 < 16; ++k4) {
            float4 xa[4], wb[4];
#pragma unroll
            for (int i = 0; i < 4; ++i) xa[i] = X4[(pq * 4 + i) * 17 + k4];
#pragma unroll
            for (int j = 0; j < 4; ++j) wb[j] = W4[(cq + 16 * j) * 17 + k4];
#pragma unroll
            for (int i = 0; i < 4; ++i)
#pragma unroll
                for (int j = 0; j < 4; ++j)
                    acc[i][j] += xa[i].x * wb[j].x + xa[i].y * wb[j].y
                               + xa[i].z * wb[j].z + xa[i].w * wb[j].w;
        }
#pragma unroll
        for (int j = 0; j < 4; ++j) {
            int c = g * 64 + cq + 16 * j;
            float bias = c1b[c];
#pragma unroll
            for (int i = 0; i < 4; ++i)
                yout[((size_t)b * NPTS + n0 + pq * 4 + i) * 128 + c] =
                    relu_f(acc[i][j] + bias);
        }
    }
}

// ---------------------------------------------------------------------------
// K5+K6 fused: mp2 = local_maxpool128(y1, idx); t2 = L2*mp2 + bias; pack.
// (unchanged R12)
// ---------------------------------------------------------------------------
__global__ __launch_bounds__(256)
void mp2lin2_mfma(const float* __restrict__ y1, const int* __restrict__ idx,
                  const u32* __restrict__ w2pk, const float* __restrict__ bias,
                  u32* __restrict__ xpk)
{
    __shared__ __align__(16) u16 Xh[8 * 64 * 8];    // 8KB
    __shared__ __align__(16) u16 Xl[8 * 64 * 8];    // 8KB
    __shared__ __align__(16) u16 Wh[8 * 128 * 8];   // 16KB
    __shared__ __align__(16) u16 Wl[8 * 128 * 8];   // 16KB

    const int chunk = blockIdx.x, b = blockIdx.y;
    const int tid = threadIdx.x;
    const int lane = tid & 63, wave = tid >> 6;
    const int l15 = lane & 15, l4 = lane >> 4;
    const int wm = wave >> 1, wn = wave & 1;        // ch-quad x pt-half

    f32x4 acc[4][2];
#pragma unroll
    for (int mt = 0; mt < 4; ++mt)
#pragma unroll
        for (int nt = 0; nt < 2; ++nt)
            acc[mt][nt] = (f32x4){0.f, 0.f, 0.f, 0.f};

    const int f4 = tid & 15;

    for (int h = 0; h < 2; ++h) {
        __syncthreads();   // protect previous-half LDS reads

        // ---- W stage: [128 ch][64 k] -> Wh/Wl [8 seg][128 ch][8] ----
        for (int u = tid; u < 1024; u += 256) {
            int row = u & 127, seg = u >> 7;
            int go = row * 128 + h * 64 + seg * 8;
            uint4 a = *(const uint4*)&w2pk[go];
            uint4 b4 = *(const uint4*)&w2pk[go + 4];
            short8 hh, ll;
            unpack8(a, b4, hh, ll);
            int lo_ = (seg * 128 + row) * 8;
            *(short8*)&Wh[lo_] = hh; *(short8*)&Wl[lo_] = ll;
        }

        // ---- X stage: gather-max 64 pts x 64 ch, split-pack to LDS ----
        for (int pass = 0; pass < 4; ++pass) {
            int ptl = pass * 16 + (tid >> 4);
            int ptg = chunk * 64 + ptl;
            const int* ip = idx + ((size_t)b * NPTS + ptg) * KNN;
            float4 mx = make_float4(-FLT_MAX, -FLT_MAX, -FLT_MAX, -FLT_MAX);
#pragma unroll
            for (int k = 0; k < KNN; ++k) {
                const float4* src = (const float4*)
                    (y1 + ((size_t)b * NPTS + ip[k]) * 128 + h * 64);
                float4 c = src[f4];
                mx.x = fmaxf(mx.x, c.x); mx.y = fmaxf(mx.y, c.y);
                mx.z = fmaxf(mx.z, c.z); mx.w = fmaxf(mx.w, c.w);
            }
            u32 p0 = bf16_split_pack(mx.x), p1 = bf16_split_pack(mx.y);
            u32 p2 = bf16_split_pack(mx.z), p3 = bf16_split_pack(mx.w);
            int seg = f4 >> 1, eb = (f4 & 1) * 4;
            int base = (seg * 64 + ptl) * 8 + eb;
            uint2 hv, lv;
            hv.x = (p0 >> 16) | (p1 & 0xFFFF0000u);
            hv.y = (p2 >> 16) | (p3 & 0xFFFF0000u);
            lv.x = (p0 & 0xFFFFu) | (p1 << 16);
            lv.y = (p2 & 0xFFFFu) | (p3 << 16);
            *(uint2*)&Xh[base] = hv;
            *(uint2*)&Xl[base] = lv;
        }
        __syncthreads();

        // ---- MFMA: 2 kb per half ----
        for (int kbl = 0; kbl < 2; ++kbl) {
            const int seg = kbl * 4 + l4;
            short8 Ah[4], Al[4], Bh[2], Bl[2];
#pragma unroll
            for (int mt = 0; mt < 4; ++mt) {
                int off = (seg * 128 + wm * 64 + mt * 16 + l15) * 8;
                Ah[mt] = *(const short8*)&Wh[off];
                Al[mt] = *(const short8*)&Wl[off];
            }
#pragma unroll
            for (int nt = 0; nt < 2; ++nt) {
                int off = (seg * 64 + wn * 32 + nt * 16 + l15) * 8;
                Bh[nt] = *(const short8*)&Xh[off];
                Bl[nt] = *(const short8*)&Xl[off];
            }
#pragma unroll
            for (int mt = 0; mt < 4; ++mt)
#pragma unroll
                for (int nt = 0; nt < 2; ++nt) {
                    acc[mt][nt] = __builtin_amdgcn_mfma_f32_16x16x32_bf16(
                        Ah[mt], Bh[nt], acc[mt][nt], 0, 0, 0);
                    acc[mt][nt] = __builtin_amdgcn_mfma_f32_16x16x32_bf16(
                        Ah[mt], Bl[nt], acc[mt][nt], 0, 0, 0);
                    acc[mt][nt] = __builtin_amdgcn_mfma_f32_16x16x32_bf16(
                        Al[mt], Bh[nt], acc[mt][nt], 0, 0, 0);
                }
        }
    }

    // ---- epilogue: t2 + bias -> split-pack -> xpk [pt][ch] ----
#pragma unroll
    for (int mt = 0; mt < 4; ++mt) {
        int ch = wm * 64 + mt * 16 + 4 * l4;
        float4 bv = *(const float4*)(bias + ch);
#pragma unroll
        for (int nt = 0; nt < 2; ++nt) {
            int ptg = chunk * 64 + wn * 32 + nt * 16 + l15;
            uint4 o;
            o.x = bf16_split_pack(acc[mt][nt][0] + bv.x);
            o.y = bf16_split_pack(acc[mt][nt][1] + bv.y);
            o.z = bf16_split_pack(acc[mt][nt][2] + bv.z);
            o.w = bf16_split_pack(acc[mt][nt][3] + bv.w);
            *(uint4*)&xpk[((size_t)b * NPTS + ptg) * 128 + ch] = o;
        }
    }
}

// ---------------------------------------------------------------------------
// K6b: split f32 weights into packed bf16 hi/lo u32. Used for c2w and l2w.
// ---------------------------------------------------------------------------
__global__ __launch_bounds__(256)
void wsplit_kernel(const float* __restrict__ w, u32* __restrict__ wpk)
{
    int t = blockIdx.x * 256 + threadIdx.x;
    wpk[t] = bf16_split_pack(w[t]);
}

// ---------------------------------------------------------------------------
// K7: conv2 (128->1024) via split-bf16 MFMA + fused max. (unchanged R9)
// ---------------------------------------------------------------------------
__global__ __launch_bounds__(256)
void conv2max_mfma(const u32* __restrict__ xpk, const u32* __restrict__ wpk,
                   const float* __restrict__ bias, float* __restrict__ pmax)
{
    __shared__ __align__(16) u16 lds[4 * 16384];   // 128 KB
    u16* Wh = lds;
    u16* Wl = lds + 16384;
    u16* Xh = lds + 2 * 16384;
    u16* Xl = lds + 3 * 16384;

    const int chunk = blockIdx.x, g = blockIdx.y, b = blockIdx.z;
    const int tid = threadIdx.x;
    const int lane = tid & 63, wave = tid >> 6;
    const int l15 = lane & 15, l4 = lane >> 4;
    const int wm = wave >> 1, wn = wave & 1;

    const u32* wp_g = wpk + (size_t)g * 128 * 128;
    const u32* xp_g = xpk + ((size_t)b * NPTS + chunk * 128) * 128;

    for (int u = tid; u < 2048; u += 256) {
        int row = u & 127, seg = u >> 7;
        int go = row * 128 + seg * 8;
        int lo_ = seg * 1024 + row * 8;
        uint4 a = *(const uint4*)&wp_g[go];
        uint4 b4 = *(const uint4*)&wp_g[go + 4];
        short8 h, l;
        unpack8(a, b4, h, l);
        *(short8*)&Wh[lo_] = h; *(short8*)&Wl[lo_] = l;
        a = *(const uint4*)&xp_g[go];
        b4 = *(const uint4*)&xp_g[go + 4];
        unpack8(a, b4, h, l);
        *(short8*)&Xh[lo_] = h; *(short8*)&Xl[lo_] = l;
    }
    __syncthreads();

    f32x4 acc[4][4];
#pragma unroll
    for (int mt = 0; mt < 4; ++mt)
#pragma unroll
        for (int nt = 0; nt < 4; ++nt)
            acc[mt][nt] = (f32x4){0.f, 0.f, 0.f, 0.f};

    for (int kb = 0; kb < 4; ++kb) {
        const int seg = kb * 4 + l4;
        short8 Ah[4], Al[4], Bh[4], Bl[4];
#pragma unroll
        for (int mt = 0; mt < 4; ++mt) {
            int off = seg * 1024 + (wm * 64 + mt * 16 + l15) * 8;
            Ah[mt] = *(const short8*)&Wh[off];
            Al[mt] = *(const short8*)&Wl[off];
        }
#pragma unroll
        for (int nt = 0; nt < 4; ++nt) {
            int off = seg * 1024 + (wn * 64 + nt * 16 + l15) * 8;
            Bh[nt] = *(const short8*)&Xh[off];
            Bl[nt] = *(const short8*)&Xl[off];
        }
#pragma unroll
        for (int mt = 0; mt < 4; ++mt)
#pragma unroll
            for (int nt = 0; nt < 4; ++nt) {
                acc[mt][nt] = __builtin_amdgcn_mfma_f32_16x16x32_bf16(
                    Ah[mt], Bh[nt], acc[mt][nt], 0, 0, 0);
                acc[mt][nt] = __builtin_amdgcn_mfma_f32_16x16x32_bf16(
                    Ah[mt], Bl[nt], acc[mt][nt], 0, 0, 0);
                acc[mt][nt] = __builtin_amdgcn_mfma_f32_16x16x32_bf16(
                    Al[mt], Bh[nt], acc[mt][nt], 0, 0, 0);
            }
    }

    __syncthreads();
    float* smax = (float*)lds;       // [128 ch][33 cols]
#pragma unroll
    for (int mt = 0; mt < 4; ++mt)
#pragma unroll
        for (int r = 0; r < 4; ++r) {
            float m = fmaxf(fmaxf(acc[mt][0][r], acc[mt][1][r]),
                            fmaxf(acc[mt][2][r], acc[mt][3][r]));
            int c = wm * 64 + mt * 16 + 4 * l4 + r;
            smax[c * 33 + wn * 16 + l15] = m;
        }
    __syncthreads();
    if (tid < 128) {
        const float* row = smax + tid * 33;
        float v = row[0];
#pragma unroll
        for (int j = 1; j < 32; ++j) v = fmaxf(v, row[j]);
        int c = g * 128 + tid;
        pmax[((size_t)b * 32 + chunk) * 1024 + c] = v + bias[c];
    }
}

// ---------------------------------------------------------------------------
// K8: reduce partial maxes over 32 chunks -> gmax [B][1024]
// ---------------------------------------------------------------------------
__global__ __launch_bounds__(256)
void gmax_kernel(const float* __restrict__ pmax, float* __restrict__ gmax)
{
    int t = blockIdx.x * 256 + threadIdx.x;
    int b = t >> 10, ch = t & 1023;
    const float* pp = pmax + (size_t)b * 32 * 1024 + ch;
    float v = -FLT_MAX;
    for (int c = 0; c < 32; ++c) v = fmaxf(v, pp[c * 1024]);
    gmax[t] = v;
}

// ---------------------------------------------------------------------------
// K9a/K9b: mlp2 split wide. grid (4, 8), block 128.
// ---------------------------------------------------------------------------
__global__ __launch_bounds__(128)
void mlp2a_kernel(const float* __restrict__ g, const float* __restrict__ w1,
                  const float* __restrict__ b1, float* __restrict__ h)
{
    __shared__ __align__(16) float sg[1024];
    const int b = blockIdx.y, tid = threadIdx.x;
    for (int i = tid; i < 1024; i += 128) sg[i] = g[b * 1024 + i];
    __syncthreads();
    const int ch = blockIdx.x * 128 + tid;
    const float4* xr = (const float4*)sg;
    const float4* wr = (const float4*)(w1 + (size_t)ch * 1024);
    float a0 = 0.f, a1 = 0.f, a2 = 0.f, a3 = 0.f;
    for (int k = 0; k < 256; ++k) {
        float4 w = wr[k], x = xr[k];
        a0 += w.x * x.x; a1 += w.y * x.y; a2 += w.z * x.z; a3 += w.w * x.w;
    }
    h[b * 512 + ch] = relu_f(b1[ch] + ((a0 + a1) + (a2 + a3)));
}

__global__ __launch_bounds__(128)
void mlp2b_kernel(const float* __restrict__ h, const float* __restrict__ w2,
                  const float* __restrict__ b2, float* __restrict__ out)
{
    __shared__ __align__(16) float sh[512];
    const int b = blockIdx.y, tid = threadIdx.x;
    for (int i = tid; i < 512; i += 128) sh[i] = h[b * 512 + i];
    __syncthreads();
    const int ch = blockIdx.x * 128 + tid;
    const float4* xr = (const float4*)sh;
    const float4* wr = (const float4*)(w2 + (size_t)ch * 512);
    float a0 = 0.f, a1 = 0.f, a2 = 0.f, a3 = 0.f;
    for (int k = 0; k < 128; ++k) {
        float4 w = wr[k], x = xr[k];
        a0 += w.x * x.x; a1 += w.y * x.y; a2 += w.z * x.z; a3 += w.w * x.w;
    }
    out[b * 512 + ch] = b2[ch] + ((a0 + a1) + (a2 + a3));
}

// ---------------------------------------------------------------------------
extern "C" void kernel_launch(void* const* d_in, const int* in_sizes, int n_in,
                              void* d_out, int out_size, void* d_ws, size_t ws_size,
                              hipStream_t stream)
{
    const float* pts  = (const float*)d_in[0];
    const float* m1w1 = (const float*)d_in[1];
    const float* m1b1 = (const float*)d_in[2];
    const float* m1w2 = (const float*)d_in[3];
    const float* m1b2 = (const float*)d_in[4];
    const float* m1w3 = (const float*)d_in[5];
    const float* m1b3 = (const float*)d_in[6];
    const float* l1w  = (const float*)d_in[7];
    const float* l1b  = (const float*)d_in[8];
    const float* c1w  = (const float*)d_in[9];
    const float* c1b  = (const float*)d_in[10];
    const float* l2w  = (const float*)d_in[11];
    const float* l2b  = (const float*)d_in[12];
    const float* c2w  = (const float*)d_in[13];
    const float* c2b  = (const float*)d_in[14];
    const float* m2w1 = (const float*)d_in[15];
    const float* m2b1 = (const float*)d_in[16];
    const float* m2w2 = (const float*)d_in[17];
    const float* m2b2 = (const float*)d_in[18];

    char* ws = (char*)d_ws;
    size_t off = 0;
    int*   idx   = (int*)(ws + off);   off += (size_t)NBATCH * NPTS * KNN * 4;
    float* h3    = (float*)(ws + off); off += (size_t)NBATCH * NPTS * 64 * 4;
    float* mp1   = (float*)(ws + off); off += (size_t)NBATCH * NPTS * 64 * 4;
    float* y1    = (float*)(ws + off); off += (size_t)NBATCH * NPTS * 128 * 4;
    u32*   xpk   = (u32*)(ws + off);   off += (size_t)NBATCH * NPTS * 128 * 4;
    float* pmaxb = (float*)(ws + off); off += (size_t)NBATCH * 64 * 1024 * 4;
    float* gmx   = (float*)(ws + off); off += (size_t)NBATCH * 1024 * 4;
    float* hbuf  = (float*)(ws + off); off += (size_t)NBATCH * 512 * 4;
    u32*   wpk   = (u32*)(ws + off);   off += (size_t)1024 * 128 * 4;
    u32*   w2pk  = (u32*)(ws + off);   off += (size_t)128 * 128 * 4;
    float4* pts4 = (float4*)(ws + off); off += (size_t)NBATCH * NPTS * 16;
    // knn partials alias xpk (xpk written later by mp2lin2, after merge):
    float* ppd   = (float*)xpk;                                           // 4MB
    int*   pix   = (int*)((char*)xpk + (size_t)NBATCH * 2 * NPTS * KNN * 4); // 4MB

    wsplit_kernel<<<dim3(512), 256, 0, stream>>>(c2w, wpk);
    wsplit_kernel<<<dim3(64), 256, 0, stream>>>(l2w, w2pk);
    pts4_kernel<<<dim3(128), 256, 0, stream>>>(pts, pts4);
    knn_half_kernel<<<dim3(64, 2, NBATCH), 256, 0, stream>>>(pts4, ppd, pix);
    knn_merge_kernel<<<dim3(128), 256, 0, stream>>>(ppd, pix, idx);
    cov_mlp1_kernel<<<dim3(64, NBATCH), 256, 0, stream>>>(pts, idx, m1w1, m1b1,
                                                          m1w2, m1b2, m1w3, m1b3, h3);
    maxpool4_kernel<16><<<dim3(NBATCH * NPTS * 16 / 256), 256, 0, stream>>>(
        (const float4*)h3, idx, (float4*)mp1);
    lin_conv1_kernel<<<dim3(64, NBATCH), 256, 0, stream>>>(mp1, l1w, l1b, c1w, c1b, y1);
    mp2lin2_mfma<<<dim3(64, NBATCH), 256, 0, stream>>>(y1, idx, w2pk, l2b, xpk);
    conv2max_mfma<<<dim3(32, 8, NBATCH), 256, 0, stream>>>(xpk, wpk, c2b, pmaxb);
    gmax_kernel<<<dim3(32), 256, 0, stream>>>(pmaxb, gmx);
    mlp2a_kernel<<<dim3(4, NBATCH), 128, 0, stream>>>(gmx, m2w1, m2b1, hbuf);
    mlp2b_kernel<<<dim3(4, NBATCH), 128, 0, stream>>>(hbuf, m2w2, m2b2, (float*)d_out);
}

// Round 14
// 282.072 us; speedup vs baseline: 1.1354x; 1.1354x over previous
//
#include <hip/hip_runtime.h>
#include <cfloat>

#define NBATCH 8
#define NPTS   4096
#define KNN    16
#define PPB    32   // points per knn block
#define NSL    8    // j-slices per point
#define CAP    24   // pass-2 collection capacity per point

typedef unsigned short u16;
typedef unsigned int   u32;
typedef __attribute__((ext_vector_type(8))) short short8;
typedef __attribute__((ext_vector_type(4))) float f32x4;

__device__ __forceinline__ float relu_f(float x) { return x > 0.f ? x : 0.f; }

// round-to-nearest-even bf16 split: x = hi + lo, packed hi<<16|lo
__device__ __forceinline__ u32 bf16_split_pack(float v)
{
    unsigned u = __float_as_uint(v);
    unsigned hb = (u + 0x7FFFu + ((u >> 16) & 1u)) >> 16;
    float hf = __uint_as_float(hb << 16);
    float l = v - hf;                      // exact
    unsigned ul = __float_as_uint(l);
    unsigned lb = (ul + 0x7FFFu + ((ul >> 16) & 1u)) >> 16;
    return (hb << 16) | (lb & 0xFFFFu);
}

// 8 packed u32 -> short8 of hi bf16 + short8 of lo bf16 (v_perm_b32)
__device__ __forceinline__ void unpack8(uint4 a, uint4 b, short8& h, short8& l)
{
    union { unsigned u[4]; short8 s; } H, L;
    H.u[0] = __builtin_amdgcn_perm(a.y, a.x, 0x07060302);
    H.u[1] = __builtin_amdgcn_perm(a.w, a.z, 0x07060302);
    H.u[2] = __builtin_amdgcn_perm(b.y, b.x, 0x07060302);
    H.u[3] = __builtin_amdgcn_perm(b.w, b.z, 0x07060302);
    L.u[0] = __builtin_amdgcn_perm(a.y, a.x, 0x05040100);
    L.u[1] = __builtin_amdgcn_perm(a.w, a.z, 0x05040100);
    L.u[2] = __builtin_amdgcn_perm(b.y, b.x, 0x05040100);
    L.u[3] = __builtin_amdgcn_perm(b.w, b.z, 0x05040100);
    h = H.s; l = L.s;
}

// ---------------------------------------------------------------------------
// K1: KNN top-16, exact two-pass. (verbatim R9/R12 — proven 120us)
// ---------------------------------------------------------------------------
__global__ __launch_bounds__(256)
void knn_kernel(const float* __restrict__ pts, int* __restrict__ idxout)
{
    __shared__ __align__(16) float4 tile[NSL * 129];      // 16.5KB
    __shared__ float  kl[PPB * NSL * 8];                  // 8KB; aliased pass2
    __shared__ float  thr[PPB];
    __shared__ int    cnt[PPB];

    const int b = blockIdx.y, tid = threadIdx.x;
    const int ptl = tid >> 3, r = tid & 7;
    const int n = blockIdx.x * PPB + ptl;
    const float* pb = pts + (size_t)b * 3 * NPTS;

    const float sx = pb[n], sy = pb[NPTS + n], sz = pb[2 * NPTS + n];

    float k8[8];
#pragma unroll
    for (int s = 0; s < 8; ++s) k8[s] = -FLT_MAX;

    const float4* slice = tile + r * 129;

    for (int t = 0; t < 4; ++t) {
        if (t) __syncthreads();
        for (int i = tid; i < 1024; i += 256) {
            int j = t * 1024 + i;
            float x = pb[j], y = pb[NPTS + j], z = pb[2 * NPTS + j];
            float xx = __fadd_rn(__fadd_rn(__fmul_rn(x, x), __fmul_rn(y, y)),
                                 __fmul_rn(z, z));
            tile[(i >> 7) * 129 + (i & 127)] = make_float4(x, y, z, xx);
        }
        __syncthreads();
#pragma unroll 8
        for (int ii = 0; ii < 128; ++ii) {
            float4 c = slice[ii];
            float dt = __fmaf_rn(sx, c.x, __fmaf_rn(sy, c.y, __fmul_rn(sz, c.z)));
            float pd = __fmaf_rn(2.f, dt, -c.w);
            float old0 = k8[0];
#pragma unroll
            for (int s = 7; s >= 1; --s)
                k8[s] = __builtin_amdgcn_fmed3f(k8[s - 1], k8[s], pd);
            k8[0] = fmaxf(old0, pd);
        }
    }

#pragma unroll
    for (int s = 0; s < 8; ++s) kl[(ptl * NSL + r) * 8 + s] = k8[s];
    __syncthreads();

    if (r == 0) {
        const float* L = kl + ptl * 64;
        int p0 = 0, p1 = 0, p2 = 0, p3 = 0, p4 = 0, p5 = 0, p6 = 0, p7 = 0;
        float tv = 0.f;
        for (int o = 0; o < 16; ++o) {
            float v0 = (p0 < 8) ? L[p0]      : -FLT_MAX;
            float v1 = (p1 < 8) ? L[8 + p1]  : -FLT_MAX;
            float v2 = (p2 < 8) ? L[16 + p2] : -FLT_MAX;
            float v3 = (p3 < 8) ? L[24 + p3] : -FLT_MAX;
            float v4 = (p4 < 8) ? L[32 + p4] : -FLT_MAX;
            float v5 = (p5 < 8) ? L[40 + p5] : -FLT_MAX;
            float v6 = (p6 < 8) ? L[48 + p6] : -FLT_MAX;
            float v7 = (p7 < 8) ? L[56 + p7] : -FLT_MAX;
            float m = fmaxf(fmaxf(fmaxf(v0, v1), fmaxf(v2, v3)),
                            fmaxf(fmaxf(v4, v5), fmaxf(v6, v7)));
            tv = m;
            if      (v0 == m) ++p0;
            else if (v1 == m) ++p1;
            else if (v2 == m) ++p2;
            else if (v3 == m) ++p3;
            else if (v4 == m) ++p4;
            else if (v5 == m) ++p5;
            else if (v6 == m) ++p6;
            else              ++p7;
        }
        thr[ptl] = tv;
        cnt[ptl] = 0;
    }
    __syncthreads();
    const float myThr = thr[ptl];

    float* pv = kl;
    int*   pi = (int*)(kl + PPB * CAP);

    for (int tt = 0; tt < 4; ++tt) {
        int t = 3 - tt;
        if (tt) {
            __syncthreads();
            for (int i = tid; i < 1024; i += 256) {
                int j = t * 1024 + i;
                float x = pb[j], y = pb[NPTS + j], z = pb[2 * NPTS + j];
                float xx = __fadd_rn(__fadd_rn(__fmul_rn(x, x), __fmul_rn(y, y)),
                                     __fmul_rn(z, z));
                tile[(i >> 7) * 129 + (i & 127)] = make_float4(x, y, z, xx);
            }
            __syncthreads();
        }
#pragma unroll 8
        for (int ii = 0; ii < 128; ++ii) {
            float4 c = slice[ii];
            float dt = __fmaf_rn(sx, c.x, __fmaf_rn(sy, c.y, __fmul_rn(sz, c.z)));
            float pd = __fmaf_rn(2.f, dt, -c.w);
            if (pd >= myThr) {
                int pos = atomicAdd(&cnt[ptl], 1);
                if (pos < CAP) {
                    pv[ptl * CAP + pos] = pd;
                    pi[ptl * CAP + pos] = t * 1024 + r * 128 + ii;
                }
            }
        }
    }
    __syncthreads();

    if (tid < PPB) {
        const int np = blockIdx.x * PPB + tid;
        int* out = idxout + ((size_t)b * NPTS + np) * KNN;
        int c = cnt[tid];
        if (c <= CAP) {
            float* v  = pv + tid * CAP;
            int*   ix = pi + tid * CAP;
            for (int o = 0; o < 16; ++o) {
                int best = o;
                for (int q = o + 1; q < c; ++q) {
                    float vq = v[q], vb = v[best];
                    if (vq > vb || (vq == vb && ix[q] < ix[best])) best = q;
                }
                float tv = v[o]; v[o] = v[best]; v[best] = tv;
                int   ti = ix[o]; ix[o] = ix[best]; ix[best] = ti;
                out[o] = ix[o];
            }
        } else {
            float qx = pb[np], qy = pb[NPTS + np], qz = pb[2 * NPTS + np];
            float v16[16]; int i16[16];
#pragma unroll
            for (int s = 0; s < 16; ++s) { v16[s] = -FLT_MAX; i16[s] = 0; }
            for (int j = 0; j < NPTS; ++j) {
                float x = pb[j], y = pb[NPTS + j], z = pb[2 * NPTS + j];
                float xx = __fadd_rn(__fadd_rn(__fmul_rn(x, x), __fmul_rn(y, y)),
                                     __fmul_rn(z, z));
                float dt = __fmaf_rn(qx, x, __fmaf_rn(qy, y, __fmul_rn(qz, z)));
                float pd = __fmaf_rn(2.f, dt, -xx);
                if (pd > v16[15]) {
                    int s = 15;
                    while (s > 0 && pd > v16[s - 1]) {
                        v16[s] = v16[s - 1]; i16[s] = i16[s - 1]; --s;
                    }
                    v16[s] = pd; i16[s] = j;
                }
            }
            for (int o = 0; o < 16; ++o) out[o] = i16[o];
        }
    }
}

// ---------------------------------------------------------------------------
// K2: local_cov + mlp1 (12->64->64->64), weights in LDS, 4x4 tiles. (unchanged)
// ---------------------------------------------------------------------------
__global__ __launch_bounds__(256)
void cov_mlp1_kernel(const float* __restrict__ pts, const int* __restrict__ idx,
                     const float* __restrict__ w1, const float* __restrict__ b1,
                     const float* __restrict__ w2, const float* __restrict__ b2,
                     const float* __restrict__ w3, const float* __restrict__ b3,
                     float* __restrict__ h3out)
{
    __shared__ __align__(16) float cov[64 * 16];
    __shared__ __align__(16) float w1s[64 * 16];
    __shared__ __align__(16) float w2s[64 * 68];
    __shared__ __align__(16) float w3s[64 * 68];
    __shared__ __align__(16) float hA[64 * 68];
    __shared__ __align__(16) float hB[64 * 68];

    const int b = blockIdx.y, tid = threadIdx.x;
    const int n0 = blockIdx.x * 64;
    const int pq = tid >> 4, cq = tid & 15;

    for (int i = tid; i < 64 * 4; i += 256) {
        int p = i >> 2, k4 = i & 3;
        float4 v = make_float4(0.f, 0.f, 0.f, 0.f);
        if (k4 < 3) v = *(const float4*)(w1 + p * 12 + k4 * 4);
        ((float4*)(w1s + p * 16))[k4] = v;
    }
    for (int i = tid; i < 64 * 16; i += 256) {
        int p = i >> 4, k4 = i & 15;
        ((float4*)(w2s + p * 68))[k4] = ((const float4*)(w2 + p * 64))[k4];
        ((float4*)(w3s + p * 68))[k4] = ((const float4*)(w3 + p * 64))[k4];
    }
    if (tid < 64) {
        const int n = n0 + tid;
        const int* ip = idx + ((size_t)b * NPTS + n) * KNN;
        int j0 = ip[0], j1 = ip[1];
        const float* pb = pts + (size_t)b * 3 * NPTS;
        float px = pb[n],  py = pb[NPTS + n],  pz = pb[2 * NPTS + n];
        float ax = pb[j0], ay = pb[NPTS + j0], az = pb[2 * NPTS + j0];
        float bx = pb[j1], by = pb[NPTS + j1], bz = pb[2 * NPTS + j1];
        float* cv = cov + tid * 16;
        cv[0] = px; cv[1] = py; cv[2] = pz;
        cv[3] = ax * bx; cv[4]  = ax * by; cv[5]  = ax * bz;
        cv[6] = ay * bx; cv[7]  = ay * by; cv[8]  = ay * bz;
        cv[9] = az * bx; cv[10] = az * by; cv[11] = az * bz;
        cv[12] = 0.f; cv[13] = 0.f; cv[14] = 0.f; cv[15] = 0.f;
    }
    __syncthreads();

    {   // layer1: 12(16)->64
        float acc[4][4];
#pragma unroll
        for (int i = 0; i < 4; ++i)
#pragma unroll
            for (int j = 0; j < 4; ++j) acc[i][j] = 0.f;
        const float4* X4 = (const float4*)cov;
        const float4* W4 = (const float4*)w1s;
#pragma unroll
        for (int k4 = 0; k4 < 4; ++k4) {
            float4 xa[4], wb[4];
#pragma unroll
            for (int i = 0; i < 4; ++i) xa[i] = X4[(pq * 4 + i) * 4 + k4];
#pragma unroll
            for (int j = 0; j < 4; ++j) wb[j] = W4[(cq + 16 * j) * 4 + k4];
#pragma unroll
            for (int i = 0; i < 4; ++i)
#pragma unroll
                for (int j = 0; j < 4; ++j)
                    acc[i][j] += xa[i].x * wb[j].x + xa[i].y * wb[j].y
                               + xa[i].z * wb[j].z + xa[i].w * wb[j].w;
        }
#pragma unroll
        for (int j = 0; j < 4; ++j) {
            int c = cq + 16 * j;
            float bias = b1[c];
#pragma unroll
            for (int i = 0; i < 4; ++i)
                hA[(pq * 4 + i) * 68 + c] = relu_f(acc[i][j] + bias);
        }
    }
    __syncthreads();

    {   // layer2: 64->64
        float acc[4][4];
#pragma unroll
        for (int i = 0; i < 4; ++i)
#pragma unroll
            for (int j = 0; j < 4; ++j) acc[i][j] = 0.f;
        const float4* X4 = (const float4*)hA;
        const float4* W4 = (const float4*)w2s;
        for (int k4 = 0; k4 < 16; ++k4) {
            float4 xa[4], wb[4];
#pragma unroll
            for (int i = 0; i < 4; ++i) xa[i] = X4[(pq * 4 + i) * 17 + k4];
#pragma unroll
            for (int j = 0; j < 4; ++j) wb[j] = W4[(cq + 16 * j) * 17 + k4];
#pragma unroll
            for (int i = 0; i < 4; ++i)
#pragma unroll
                for (int j = 0; j < 4; ++j)
                    acc[i][j] += xa[i].x * wb[j].x + xa[i].y * wb[j].y
                               + xa[i].z * wb[j].z + xa[i].w * wb[j].w;
        }
#pragma unroll
        for (int j = 0; j < 4; ++j) {
            int c = cq + 16 * j;
            float bias = b2[c];
#pragma unroll
            for (int i = 0; i < 4; ++i)
                hB[(pq * 4 + i) * 68 + c] = relu_f(acc[i][j] + bias);
        }
    }
    __syncthreads();

    {   // layer3: 64->64 -> global
        float acc[4][4];
#pragma unroll
        for (int i = 0; i < 4; ++i)
#pragma unroll
            for (int j = 0; j < 4; ++j) acc[i][j] = 0.f;
        const float4* X4 = (const float4*)hB;
        const float4* W4 = (const float4*)w3s;
        for (int k4 = 0; k4 < 16; ++k4) {
            float4 xa[4], wb[4];
#pragma unroll
            for (int i = 0; i < 4; ++i) xa[i] = X4[(pq * 4 + i) * 17 + k4];
#pragma unroll
            for (int j = 0; j < 4; ++j) wb[j] = W4[(cq + 16 * j) * 17 + k4];
#pragma unroll
            for (int i = 0; i < 4; ++i)
#pragma unroll
                for (int j = 0; j < 4; ++j)
                    acc[i][j] += xa[i].x * wb[j].x + xa[i].y * wb[j].y
                               + xa[i].z * wb[j].z + xa[i].w * wb[j].w;
        }
#pragma unroll
        for (int j = 0; j < 4; ++j) {
            int c = cq + 16 * j;
            float bias = b3[c];
#pragma unroll
            for (int i = 0; i < 4; ++i)
                h3out[((size_t)b * NPTS + n0 + pq * 4 + i) * 64 + c] =
                    relu_f(acc[i][j] + bias);
        }
    }
}

// ---------------------------------------------------------------------------
// K3: neighbor max-pool (64ch), float4 per thread.
// ---------------------------------------------------------------------------
template <int DV4>
__global__ __launch_bounds__(256)
void maxpool4_kernel(const float4* __restrict__ f, const int* __restrict__ idx,
                     float4* __restrict__ out)
{
    constexpr int SH = (DV4 == 16) ? 4 : 5;
    int t = blockIdx.x * 256 + threadIdx.x;
    int d4 = t & (DV4 - 1);
    int n  = (t >> SH) & (NPTS - 1);
    int b  = t >> (SH + 12);
    const int* ip = idx + ((size_t)b * NPTS + n) * KNN;
    const float4* fb = f + (size_t)b * NPTS * DV4;
    float4 v = make_float4(-FLT_MAX, -FLT_MAX, -FLT_MAX, -FLT_MAX);
#pragma unroll
    for (int k = 0; k < KNN; ++k) {
        float4 c = fb[(size_t)ip[k] * DV4 + d4];
        v.x = fmaxf(v.x, c.x); v.y = fmaxf(v.y, c.y);
        v.z = fmaxf(v.z, c.z); v.w = fmaxf(v.w, c.w);
    }
    out[t] = v;
}

// ---------------------------------------------------------------------------
// K4: lin_conv1 via split-bf16 MFMA: t1 = L1(64->64)+bias (no relu);
// y1 = relu(C1(64->128)+bias), f32 out. grid (64 ptchunks, 8 batch),
// block 256 = 4 waves. LDS 48KB: Wh/Wl [8 seg][<=128 row][8],
// Xh/Xl [8 seg][64 pt][8]. t1 split-packed in-register between GEMMs.
// Same fragment conventions as mp2lin2/conv2max (proven).
// ---------------------------------------------------------------------------
__global__ __launch_bounds__(256)
void lin_conv1_mfma(const float* __restrict__ mp1, const u32* __restrict__ l1pk,
                    const float* __restrict__ l1b, const u32* __restrict__ c1pk,
                    const float* __restrict__ c1b, float* __restrict__ y1)
{
    __shared__ __align__(16) u16 lds[24576];   // 48 KB
    u16* Wh = lds;               // up to [8][128][8] = 8192 u16
    u16* Wl = lds + 8192;
    u16* Xh = lds + 16384;       // [8][64][8] = 4096 u16
    u16* Xl = lds + 20480;

    const int chunk = blockIdx.x, b = blockIdx.y;
    const int tid = threadIdx.x;
    const int lane = tid & 63, wave = tid >> 6;
    const int l15 = lane & 15, l4 = lane >> 4;
    const int wm = wave >> 1, wn = wave & 1;

    // ---- stage X (mp1, f32) split-packed -> Xh/Xl [seg][pt][8] ----
    for (int u = tid; u < 512; u += 256) {
        int pt = u >> 3, seg = u & 7;
        const float* src = mp1 + ((size_t)b * NPTS + chunk * 64 + pt) * 64 + seg * 8;
        float4 a = *(const float4*)src, c = *(const float4*)(src + 4);
        float v[8] = {a.x, a.y, a.z, a.w, c.x, c.y, c.z, c.w};
        union { u16 u[8]; short8 s; } H, L;
#pragma unroll
        for (int e = 0; e < 8; ++e) {
            u32 p = bf16_split_pack(v[e]);
            H.u[e] = (u16)(p >> 16); L.u[e] = (u16)p;
        }
        int lo_ = (seg * 64 + pt) * 8;
        *(short8*)&Xh[lo_] = H.s; *(short8*)&Xl[lo_] = L.s;
    }
    // ---- stage W = l1pk [64 ch][64 k] -> Wh/Wl [seg][64 ch][8] ----
    for (int u = tid; u < 512; u += 256) {
        int ch = u >> 3, seg = u & 7;
        const u32* src = l1pk + ch * 64 + seg * 8;
        uint4 a = *(const uint4*)src, b4 = *(const uint4*)(src + 4);
        short8 h, l;
        unpack8(a, b4, h, l);
        int lo_ = (seg * 64 + ch) * 8;
        *(short8*)&Wh[lo_] = h; *(short8*)&Wl[lo_] = l;
    }
    __syncthreads();

    // ---- MFMA L1: M=64 ch, N=64 pt; wave quadrant 32x32 ----
    f32x4 acc1[2][2];
#pragma unroll
    for (int mt = 0; mt < 2; ++mt)
#pragma unroll
        for (int nt = 0; nt < 2; ++nt)
            acc1[mt][nt] = (f32x4){0.f, 0.f, 0.f, 0.f};

    for (int kb = 0; kb < 2; ++kb) {
        const int seg = kb * 4 + l4;
        short8 Ah[2], Al[2], Bh[2], Bl[2];
#pragma unroll
        for (int mt = 0; mt < 2; ++mt) {
            int off = (seg * 64 + wm * 32 + mt * 16 + l15) * 8;
            Ah[mt] = *(const short8*)&Wh[off];
            Al[mt] = *(const short8*)&Wl[off];
        }
#pragma unroll
        for (int nt = 0; nt < 2; ++nt) {
            int off = (seg * 64 + wn * 32 + nt * 16 + l15) * 8;
            Bh[nt] = *(const short8*)&Xh[off];
            Bl[nt] = *(const short8*)&Xl[off];
        }
#pragma unroll
        for (int mt = 0; mt < 2; ++mt)
#pragma unroll
            for (int nt = 0; nt < 2; ++nt) {
                acc1[mt][nt] = __builtin_amdgcn_mfma_f32_16x16x32_bf16(
                    Ah[mt], Bh[nt], acc1[mt][nt], 0, 0, 0);
                acc1[mt][nt] = __builtin_amdgcn_mfma_f32_16x16x32_bf16(
                    Ah[mt], Bl[nt], acc1[mt][nt], 0, 0, 0);
                acc1[mt][nt] = __builtin_amdgcn_mfma_f32_16x16x32_bf16(
                    Al[mt], Bh[nt], acc1[mt][nt], 0, 0, 0);
            }
    }
    __syncthreads();   // all L1 reads of Xh/Xl/Wh/Wl done

    // ---- t1 = acc1 + l1b -> split-pack back into Xh/Xl ([seg][pt][8], k=ch)
#pragma unroll
    for (int mt = 0; mt < 2; ++mt)
#pragma unroll
        for (int nt = 0; nt < 2; ++nt) {
            int pt = wn * 32 + nt * 16 + l15;
#pragma unroll
            for (int r = 0; r < 4; ++r) {
                int ch = wm * 32 + mt * 16 + 4 * l4 + r;
                u32 p = bf16_split_pack(acc1[mt][nt][r] + l1b[ch]);
                int o = ((ch >> 3) * 64 + pt) * 8 + (ch & 7);
                Xh[o] = (u16)(p >> 16); Xl[o] = (u16)p;
            }
        }
    // ---- stage W = c1pk [128 ch][64 k] -> Wh/Wl [seg][128 ch][8] ----
    for (int u = tid; u < 1024; u += 256) {
        int ch = u >> 3, seg = u & 7;
        const u32* src = c1pk + ch * 64 + seg * 8;
        uint4 a = *(const uint4*)src, b4 = *(const uint4*)(src + 4);
        short8 h, l;
        unpack8(a, b4, h, l);
        int lo_ = (seg * 128 + ch) * 8;
        *(short8*)&Wh[lo_] = h; *(short8*)&Wl[lo_] = l;
    }
    __syncthreads();

    // ---- MFMA C1: M=128 ch, N=64 pt; wave = 64ch x 32pt ----
    f32x4 acc2[4][2];
#pragma unroll
    for (int mt = 0; mt < 4; ++mt)
#pragma unroll
        for (int nt = 0; nt < 2; ++nt)
            acc2[mt][nt] = (f32x4){0.f, 0.f, 0.f, 0.f};

    for (int kb = 0; kb < 2; ++kb) {
        const int seg = kb * 4 + l4;
        short8 Ah[4], Al[4], Bh[2], Bl[2];
#pragma unroll
        for (int mt = 0; mt < 4; ++mt) {
            int off = (seg * 128 + wm * 64 + mt * 16 + l15) * 8;
            Ah[mt] = *(const short8*)&Wh[off];
            Al[mt] = *(const short8*)&Wl[off];
        }
#pragma unroll
        for (int nt = 0; nt < 2; ++nt) {
            int off = (seg * 64 + wn * 32 + nt * 16 + l15) * 8;
            Bh[nt] = *(const short8*)&Xh[off];
            Bl[nt] = *(const short8*)&Xl[off];
        }
#pragma unroll
        for (int mt = 0; mt < 4; ++mt)
#pragma unroll
            for (int nt = 0; nt < 2; ++nt) {
                acc2[mt][nt] = __builtin_amdgcn_mfma_f32_16x16x32_bf16(
                    Ah[mt], Bh[nt], acc2[mt][nt], 0, 0, 0);
                acc2[mt][nt] = __builtin_amdgcn_mfma_f32_16x16x32_bf16(
                    Ah[mt], Bl[nt], acc2[mt][nt], 0, 0, 0);
                acc2[mt][nt] = __builtin_amdgcn_mfma_f32_16x16x32_bf16(
                    Al[mt], Bh[nt], acc2[mt][nt], 0, 0, 0);
            }
    }
    __syncthreads();   // X/W dead; reuse LDS as f32 [64 pt][132 ch]

    float* yst = (float*)lds;
#pragma unroll
    for (int mt = 0; mt < 4; ++mt)
#pragma unroll
        for (int nt = 0; nt < 2; ++nt) {
            int pt = wn * 32 + nt * 16 + l15;
#pragma unroll
            for (int r = 0; r < 4; ++r) {
                int ch = wm * 64 + mt * 16 + 4 * l4 + r;
                yst[pt * 132 + ch] = relu_f(acc2[mt][nt][r] + c1b[ch]);
            }
        }
    __syncthreads();
    for (int u = tid; u < 2048; u += 256) {
        int pt = u >> 5, q = u & 31;
        *(float4*)(y1 + ((size_t)b * NPTS + chunk * 64 + pt) * 128 + q * 4) =
            *(const float4*)(yst + pt * 132 + q * 4);
    }
}

// ---------------------------------------------------------------------------
// K5+K6 fused: mp2 = local_maxpool128(y1, idx); t2 = L2*mp2 + bias; pack.
// (unchanged R12)
// ---------------------------------------------------------------------------
__global__ __launch_bounds__(256)
void mp2lin2_mfma(const float* __restrict__ y1, const int* __restrict__ idx,
                  const u32* __restrict__ w2pk, const float* __restrict__ bias,
                  u32* __restrict__ xpk)
{
    __shared__ __align__(16) u16 Xh[8 * 64 * 8];    // 8KB
    __shared__ __align__(16) u16 Xl[8 * 64 * 8];    // 8KB
    __shared__ __align__(16) u16 Wh[8 * 128 * 8];   // 16KB
    __shared__ __align__(16) u16 Wl[8 * 128 * 8];   // 16KB

    const int chunk = blockIdx.x, b = blockIdx.y;
    const int tid = threadIdx.x;
    const int lane = tid & 63, wave = tid >> 6;
    const int l15 = lane & 15, l4 = lane >> 4;
    const int wm = wave >> 1, wn = wave & 1;

    f32x4 acc[4][2];
#pragma unroll
    for (int mt = 0; mt < 4; ++mt)
#pragma unroll
        for (int nt = 0; nt < 2; ++nt)
            acc[mt][nt] = (f32x4){0.f, 0.f, 0.f, 0.f};

    const int f4 = tid & 15;

    for (int h = 0; h < 2; ++h) {
        __syncthreads();

        for (int u = tid; u < 1024; u += 256) {
            int row = u & 127, seg = u >> 7;
            int go = row * 128 + h * 64 + seg * 8;
            uint4 a = *(const uint4*)&w2pk[go];
            uint4 b4 = *(const uint4*)&w2pk[go + 4];
            short8 hh, ll;
            unpack8(a, b4, hh, ll);
            int lo_ = (seg * 128 + row) * 8;
            *(short8*)&Wh[lo_] = hh; *(short8*)&Wl[lo_] = ll;
        }

        for (int pass = 0; pass < 4; ++pass) {
            int ptl = pass * 16 + (tid >> 4);
            int ptg = chunk * 64 + ptl;
            const int* ip = idx + ((size_t)b * NPTS + ptg) * KNN;
            float4 mx = make_float4(-FLT_MAX, -FLT_MAX, -FLT_MAX, -FLT_MAX);
#pragma unroll
            for (int k = 0; k < KNN; ++k) {
                const float4* src = (const float4*)
                    (y1 + ((size_t)b * NPTS + ip[k]) * 128 + h * 64);
                float4 c = src[f4];
                mx.x = fmaxf(mx.x, c.x); mx.y = fmaxf(mx.y, c.y);
                mx.z = fmaxf(mx.z, c.z); mx.w = fmaxf(mx.w, c.w);
            }
            u32 p0 = bf16_split_pack(mx.x), p1 = bf16_split_pack(mx.y);
            u32 p2 = bf16_split_pack(mx.z), p3 = bf16_split_pack(mx.w);
            int seg = f4 >> 1, eb = (f4 & 1) * 4;
            int base = (seg * 64 + ptl) * 8 + eb;
            uint2 hv, lv;
            hv.x = (p0 >> 16) | (p1 & 0xFFFF0000u);
            hv.y = (p2 >> 16) | (p3 & 0xFFFF0000u);
            lv.x = (p0 & 0xFFFFu) | (p1 << 16);
            lv.y = (p2 & 0xFFFFu) | (p3 << 16);
            *(uint2*)&Xh[base] = hv;
            *(uint2*)&Xl[base] = lv;
        }
        __syncthreads();

        for (int kbl = 0; kbl < 2; ++kbl) {
            const int seg = kbl * 4 + l4;
            short8 Ah[4], Al[4], Bh[2], Bl[2];
#pragma unroll
            for (int mt = 0; mt < 4; ++mt) {
                int off = (seg * 128 + wm * 64 + mt * 16 + l15) * 8;
                Ah[mt] = *(const short8*)&Wh[off];
                Al[mt] = *(const short8*)&Wl[off];
            }
#pragma unroll
            for (int nt = 0; nt < 2; ++nt) {
                int off = (seg * 64 + wn * 32 + nt * 16 + l15) * 8;
                Bh[nt] = *(const short8*)&Xh[off];
                Bl[nt] = *(const short8*)&Xl[off];
            }
#pragma unroll
            for (int mt = 0; mt < 4; ++mt)
#pragma unroll
                for (int nt = 0; nt < 2; ++nt) {
                    acc[mt][nt] = __builtin_amdgcn_mfma_f32_16x16x32_bf16(
                        Ah[mt], Bh[nt], acc[mt][nt], 0, 0, 0);
                    acc[mt][nt] = __builtin_amdgcn_mfma_f32_16x16x32_bf16(
                        Ah[mt], Bl[nt], acc[mt][nt], 0, 0, 0);
                    acc[mt][nt] = __builtin_amdgcn_mfma_f32_16x16x32_bf16(
                        Al[mt], Bh[nt], acc[mt][nt], 0, 0, 0);
                }
        }
    }

#pragma unroll
    for (int mt = 0; mt < 4; ++mt) {
        int ch = wm * 64 + mt * 16 + 4 * l4;
        float4 bv = *(const float4*)(bias + ch);
#pragma unroll
        for (int nt = 0; nt < 2; ++nt) {
            int ptg = chunk * 64 + wn * 32 + nt * 16 + l15;
            uint4 o;
            o.x = bf16_split_pack(acc[mt][nt][0] + bv.x);
            o.y = bf16_split_pack(acc[mt][nt][1] + bv.y);
            o.z = bf16_split_pack(acc[mt][nt][2] + bv.z);
            o.w = bf16_split_pack(acc[mt][nt][3] + bv.w);
            *(uint4*)&xpk[((size_t)b * NPTS + ptg) * 128 + ch] = o;
        }
    }
}

// ---------------------------------------------------------------------------
// K6b: split f32 weights into packed bf16 hi/lo u32.
// ---------------------------------------------------------------------------
__global__ __launch_bounds__(256)
void wsplit_kernel(const float* __restrict__ w, u32* __restrict__ wpk)
{
    int t = blockIdx.x * 256 + threadIdx.x;
    wpk[t] = bf16_split_pack(w[t]);
}

// ---------------------------------------------------------------------------
// K7: conv2 (128->1024) via split-bf16 MFMA + fused max. (unchanged R9)
// ---------------------------------------------------------------------------
__global__ __launch_bounds__(256)
void conv2max_mfma(const u32* __restrict__ xpk, const u32* __restrict__ wpk,
                   const float* __restrict__ bias, float* __restrict__ pmax)
{
    __shared__ __align__(16) u16 lds[4 * 16384];   // 128 KB
    u16* Wh = lds;
    u16* Wl = lds + 16384;
    u16* Xh = lds + 2 * 16384;
    u16* Xl = lds + 3 * 16384;

    const int chunk = blockIdx.x, g = blockIdx.y, b = blockIdx.z;
    const int tid = threadIdx.x;
    const int lane = tid & 63, wave = tid >> 6;
    const int l15 = lane & 15, l4 = lane >> 4;
    const int wm = wave >> 1, wn = wave & 1;

    const u32* wp_g = wpk + (size_t)g * 128 * 128;
    const u32* xp_g = xpk + ((size_t)b * NPTS + chunk * 128) * 128;

    for (int u = tid; u < 2048; u += 256) {
        int row = u & 127, seg = u >> 7;
        int go = row * 128 + seg * 8;
        int lo_ = seg * 1024 + row * 8;
        uint4 a = *(const uint4*)&wp_g[go];
        uint4 b4 = *(const uint4*)&wp_g[go + 4];
        short8 h, l;
        unpack8(a, b4, h, l);
        *(short8*)&Wh[lo_] = h; *(short8*)&Wl[lo_] = l;
        a = *(const uint4*)&xp_g[go];
        b4 = *(const uint4*)&xp_g[go + 4];
        unpack8(a, b4, h, l);
        *(short8*)&Xh[lo_] = h; *(short8*)&Xl[lo_] = l;
    }
    __syncthreads();

    f32x4 acc[4][4];
#pragma unroll
    for (int mt = 0; mt < 4; ++mt)
#pragma unroll
        for (int nt = 0; nt < 4; ++nt)
            acc[mt][nt] = (f32x4){0.f, 0.f, 0.f, 0.f};

    for (int kb = 0; kb < 4; ++kb) {
        const int seg = kb * 4 + l4;
        short8 Ah[4], Al[4], Bh[4], Bl[4];
#pragma unroll
        for (int mt = 0; mt < 4; ++mt) {
            int off = seg * 1024 + (wm * 64 + mt * 16 + l15) * 8;
            Ah[mt] = *(const short8*)&Wh[off];
            Al[mt] = *(const short8*)&Wl[off];
        }
#pragma unroll
        for (int nt = 0; nt < 4; ++nt) {
            int off = seg * 1024 + (wn * 64 + nt * 16 + l15) * 8;
            Bh[nt] = *(const short8*)&Xh[off];
            Bl[nt] = *(const short8*)&Xl[off];
        }
#pragma unroll
        for (int mt = 0; mt < 4; ++mt)
#pragma unroll
            for (int nt = 0; nt < 4; ++nt) {
                acc[mt][nt] = __builtin_amdgcn_mfma_f32_16x16x32_bf16(
                    Ah[mt], Bh[nt], acc[mt][nt], 0, 0, 0);
                acc[mt][nt] = __builtin_amdgcn_mfma_f32_16x16x32_bf16(
                    Ah[mt], Bl[nt], acc[mt][nt], 0, 0, 0);
                acc[mt][nt] = __builtin_amdgcn_mfma_f32_16x16x32_bf16(
                    Al[mt], Bh[nt], acc[mt][nt], 0, 0, 0);
            }
    }

    __syncthreads();
    float* smax = (float*)lds;       // [128 ch][33 cols]
#pragma unroll
    for (int mt = 0; mt < 4; ++mt)
#pragma unroll
        for (int r = 0; r < 4; ++r) {
            float m = fmaxf(fmaxf(acc[mt][0][r], acc[mt][1][r]),
                            fmaxf(acc[mt][2][r], acc[mt][3][r]));
            int c = wm * 64 + mt * 16 + 4 * l4 + r;
            smax[c * 33 + wn * 16 + l15] = m;
        }
    __syncthreads();
    if (tid < 128) {
        const float* row = smax + tid * 33;
        float v = row[0];
#pragma unroll
        for (int j = 1; j < 32; ++j) v = fmaxf(v, row[j]);
        int c = g * 128 + tid;
        pmax[((size_t)b * 32 + chunk) * 1024 + c] = v + bias[c];
    }
}

// ---------------------------------------------------------------------------
// K8: reduce partial maxes over 32 chunks -> gmax [B][1024]
// ---------------------------------------------------------------------------
__global__ __launch_bounds__(256)
void gmax_kernel(const float* __restrict__ pmax, float* __restrict__ gmax)
{
    int t = blockIdx.x * 256 + threadIdx.x;
    int b = t >> 10, ch = t & 1023;
    const float* pp = pmax + (size_t)b * 32 * 1024 + ch;
    float v = -FLT_MAX;
    for (int c = 0; c < 32; ++c) v = fmaxf(v, pp[c * 1024]);
    gmax[t] = v;
}

// ---------------------------------------------------------------------------
// K9a/K9b: mlp2 split wide. grid (4, 8), block 128.
// ---------------------------------------------------------------------------
__global__ __launch_bounds__(128)
void mlp2a_kernel(const float* __restrict__ g, const float* __restrict__ w1,
                  const float* __restrict__ b1, float* __restrict__ h)
{
    __shared__ __align__(16) float sg[1024];
    const int b = blockIdx.y, tid = threadIdx.x;
    for (int i = tid; i < 1024; i += 128) sg[i] = g[b * 1024 + i];
    __syncthreads();
    const int ch = blockIdx.x * 128 + tid;
    const float4* xr = (const float4*)sg;
    const float4* wr = (const float4*)(w1 + (size_t)ch * 1024);
    float a0 = 0.f, a1 = 0.f, a2 = 0.f, a3 = 0.f;
    for (int k = 0; k < 256; ++k) {
        float4 w = wr[k], x = xr[k];
        a0 += w.x * x.x; a1 += w.y * x.y; a2 += w.z * x.z; a3 += w.w * x.w;
    }
    h[b * 512 + ch] = relu_f(b1[ch] + ((a0 + a1) + (a2 + a3)));
}

__global__ __launch_bounds__(128)
void mlp2b_kernel(const float* __restrict__ h, const float* __restrict__ w2,
                  const float* __restrict__ b2, float* __restrict__ out)
{
    __shared__ __align__(16) float sh[512];
    const int b = blockIdx.y, tid = threadIdx.x;
    for (int i = tid; i < 512; i += 128) sh[i] = h[b * 512 + i];
    __syncthreads();
    const int ch = blockIdx.x * 128 + tid;
    const float4* xr = (const float4*)sh;
    const float4* wr = (const float4*)(w2 + (size_t)ch * 512);
    float a0 = 0.f, a1 = 0.f, a2 = 0.f, a3 = 0.f;
    for (int k = 0; k < 128; ++k) {
        float4 w = wr[k], x = xr[k];
        a0 += w.x * x.x; a1 += w.y * x.y; a2 += w.z * x.z; a3 += w.w * x.w;
    }
    out[b * 512 + ch] = b2[ch] + ((a0 + a1) + (a2 + a3));
}

// ---------------------------------------------------------------------------
extern "C" void kernel_launch(void* const* d_in, const int* in_sizes, int n_in,
                              void* d_out, int out_size, void* d_ws, size_t ws_size,
                              hipStream_t stream)
{
    const float* pts  = (const float*)d_in[0];
    const float* m1w1 = (const float*)d_in[1];
    const float* m1b1 = (const float*)d_in[2];
    const float* m1w2 = (const float*)d_in[3];
    const float* m1b2 = (const float*)d_in[4];
    const float* m1w3 = (const float*)d_in[5];
    const float* m1b3 = (const float*)d_in[6];
    const float* l1w  = (const float*)d_in[7];
    const float* l1b  = (const float*)d_in[8];
    const float* c1w  = (const float*)d_in[9];
    const float* c1b  = (const float*)d_in[10];
    const float* l2w  = (const float*)d_in[11];
    const float* l2b  = (const float*)d_in[12];
    const float* c2w  = (const float*)d_in[13];
    const float* c2b  = (const float*)d_in[14];
    const float* m2w1 = (const float*)d_in[15];
    const float* m2b1 = (const float*)d_in[16];
    const float* m2w2 = (const float*)d_in[17];
    const float* m2b2 = (const float*)d_in[18];

    char* ws = (char*)d_ws;
    size_t off = 0;
    int*   idx   = (int*)(ws + off);   off += (size_t)NBATCH * NPTS * KNN * 4;
    float* h3    = (float*)(ws + off); off += (size_t)NBATCH * NPTS * 64 * 4;
    float* mp1   = (float*)(ws + off); off += (size_t)NBATCH * NPTS * 64 * 4;
    float* y1    = (float*)(ws + off); off += (size_t)NBATCH * NPTS * 128 * 4;
    u32*   xpk   = (u32*)(ws + off);   off += (size_t)NBATCH * NPTS * 128 * 4;
    float* pmaxb = (float*)(ws + off); off += (size_t)NBATCH * 64 * 1024 * 4;
    float* gmx   = (float*)(ws + off); off += (size_t)NBATCH * 1024 * 4;
    float* hbuf  = (float*)(ws + off); off += (size_t)NBATCH * 512 * 4;
    u32*   wpk   = (u32*)(ws + off);   off += (size_t)1024 * 128 * 4;
    u32*   w2pk  = (u32*)(ws + off);   off += (size_t)128 * 128 * 4;
    u32*   l1pk  = (u32*)(ws + off);   off += (size_t)64 * 64 * 4;
    u32*   c1pk  = (u32*)(ws + off);   off += (size_t)128 * 64 * 4;

    wsplit_kernel<<<dim3(512), 256, 0, stream>>>(c2w, wpk);
    wsplit_kernel<<<dim3(64), 256, 0, stream>>>(l2w, w2pk);
    wsplit_kernel<<<dim3(16), 256, 0, stream>>>(l1w, l1pk);
    wsplit_kernel<<<dim3(32), 256, 0, stream>>>(c1w, c1pk);
    knn_kernel<<<dim3(NPTS / PPB, NBATCH), 256, 0, stream>>>(pts, idx);
    cov_mlp1_kernel<<<dim3(64, NBATCH), 256, 0, stream>>>(pts, idx, m1w1, m1b1,
                                                          m1w2, m1b2, m1w3, m1b3, h3);
    maxpool4_kernel<16><<<dim3(NBATCH * NPTS * 16 / 256), 256, 0, stream>>>(
        (const float4*)h3, idx, (float4*)mp1);
    lin_conv1_mfma<<<dim3(64, NBATCH), 256, 0, stream>>>(mp1, l1pk, l1b,
                                                         c1pk, c1b, y1);
    mp2lin2_mfma<<<dim3(64, NBATCH), 256, 0, stream>>>(y1, idx, w2pk, l2b, xpk);
    conv2max_mfma<<<dim3(32, 8, NBATCH), 256, 0, stream>>>(xpk, wpk, c2b, pmaxb);
    gmax_kernel<<<dim3(32), 256, 0, stream>>>(pmaxb, gmx);
    mlp2a_kernel<<<dim3(4, NBATCH), 128, 0, stream>>>(gmx, m2w1, m2b1, hbuf);
    mlp2b_kernel<<<dim3(4, NBATCH), 128, 0, stream>>>(hbuf, m2w2, m2b2, (float*)d_out);
}